// Round 7
// baseline (1940.689 us; speedup 1.0000x reference)
//
#include <hip/hip_runtime.h>

// MultiAgentDRQN R7. R6 post-mortem: fc1 VGPR=108 (<128 weight floats!) ->
// compiler rematerialized weights from memory in-loop; 1-row lookahead < HBM
// latency -> stall-bound 300us. Fixes:
//   fc1: weights as float4 w1v[32]; TWO-slot lookahead (qA/qB, 2x unroll):
//        load->use distance = 2 rows (~900cy). grid 1024, bounds(256,2).
//   gru3: W2 slice moved from 16 VGPRs to LDS broadcast (single-wave block:
//        no barrier needed); guards the 256-VGPR spill cliff.
//   gi: unchanged (distance-3 prefetch already covers latency).
// All fp32 (argmax-flip safety). Fallback: R1 fused kernel if ws too small.

namespace {
constexpr int kB = 256, kT = 200, kN = 8, kObs = 128, kH = 64, kOut = 16;
constexpr int kRows = kB * kT * kN;                  // 409600
constexpr size_t kABytes  = (size_t)kRows * 64 * 4;  // 100 MB
constexpr size_t kGiBytes = (size_t)kRows * 192 * 4; // 300 MB
}

// ---------------- fc1_k: a[r][64] = relu(x_r . W1^T + b1) --------------------
__global__ __launch_bounds__(256, 2)
void fc1_k(const float* __restrict__ obs, const int* __restrict__ agent,
           const float* __restrict__ W1, const float* __restrict__ b1,
           float* __restrict__ a_out) {
  __shared__ float xs[4][2][128];
  __shared__ float ohs[512];  // ohs[n*64+l] = W1[l][128+agent[n]]
  const int tid = threadIdx.x, lane = tid & 63, w = tid >> 6;
  for (int i = tid; i < 512; i += 256) {
    int n = i >> 6, l = i & 63;
    ohs[i] = W1[(size_t)l * 136 + 128 + agent[n]];
  }
  __syncthreads();

  float4 w1v[32];
  #pragma unroll
  for (int k = 0; k < 32; ++k)
    w1v[k] = *(const float4*)(W1 + (size_t)lane * 136 + k * 4);
  const float b1r = b1[lane];

  constexpr int ROWS = 100;               // 4096 waves x 100 rows
  const int gwave = blockIdx.x * 4 + w;
  const int r0 = gwave * ROWS;
  float (*xw)[128] = xs[w];

  // prologue: xw[0] = x(0); qA = x(1), qB = x(2)
  *(float2*)(xw[0] + lane * 2) =
      *(const float2*)(obs + (size_t)r0 * 128 + lane * 2);
  float2 qA = *(const float2*)(obs + (size_t)(r0 + 1) * 128 + lane * 2);
  float2 qB = *(const float2*)(obs + (size_t)(r0 + 2) * 128 + lane * 2);

#define FC1_BODY(I, Q, NEXT)                                                   \
  {                                                                            \
    const int i_ = (I);                                                        \
    if (i_ + 1 < ROWS) *(float2*)(xw[(i_ + 1) & 1] + lane * 2) = Q;            \
    const int nr_ = (NEXT) < ROWS ? (NEXT) : (ROWS - 1);                       \
    Q = *(const float2*)(obs + (size_t)(r0 + nr_) * 128 + lane * 2);           \
    const float* xb_ = xw[i_ & 1];                                             \
    float a0 = 0.f, a1 = 0.f, a2 = 0.f, a3 = 0.f;                              \
    _Pragma("unroll") for (int k = 0; k < 32; ++k) {                           \
      float4 xp = *(const float4*)(xb_ + k * 4);                               \
      a0 = fmaf(w1v[k].x, xp.x, a0);                                           \
      a1 = fmaf(w1v[k].y, xp.y, a1);                                           \
      a2 = fmaf(w1v[k].z, xp.z, a2);                                           \
      a3 = fmaf(w1v[k].w, xp.w, a3);                                           \
    }                                                                          \
    const int r_ = r0 + i_;                                                    \
    float av = (a0 + a1) + (a2 + a3) + b1r + ohs[(r_ & 7) * 64 + lane];        \
    a_out[(size_t)r_ * 64 + lane] = fmaxf(av, 0.f);                            \
  }

  #pragma unroll 1
  for (int i = 0; i < ROWS; i += 2) {
    FC1_BODY(i + 0, qA, i + 3)
    FC1_BODY(i + 1, qB, i + 4)
  }
#undef FC1_BODY
}

// ---------------- gi_k: gi[r][192] = Wih . a_r + bih -------------------------
__global__ __launch_bounds__(256, 2)
void gi_k(const float* __restrict__ a_glob, const float* __restrict__ Wih,
          const float* __restrict__ bih, float* __restrict__ gi_out) {
  __shared__ float as_[4][2][64];
  const int tid = threadIdx.x, lane = tid & 63, w = tid >> 6;

  float wir[64], wiz[64], win_[64];
  #pragma unroll
  for (int k = 0; k < 64; k += 4) {
    *(float4*)&wir[k]  = *(const float4*)(Wih + (size_t)lane * 64 + k);
    *(float4*)&wiz[k]  = *(const float4*)(Wih + (size_t)(64 + lane) * 64 + k);
    *(float4*)&win_[k] = *(const float4*)(Wih + (size_t)(128 + lane) * 64 + k);
  }
  const float bir = bih[lane], biz = bih[64 + lane], bin_ = bih[128 + lane];

  const int gwave = blockIdx.x * 4 + w;   // 2048 waves x 200 rows
  const int r0 = gwave * 200;
  float (*ab)[64] = as_[w];

  ab[0][lane] = a_glob[(size_t)r0 * 64 + lane];
  float qA = a_glob[(size_t)(r0 + 1) * 64 + lane];
  float qB = a_glob[(size_t)(r0 + 2) * 64 + lane];

#define GI_BODY(T, Q, NEXT)                                                    \
  {                                                                            \
    const int t_ = (T);                                                        \
    if (t_ < 199) ab[(t_ + 1) & 1][lane] = Q;                                  \
    const int nr_ = (NEXT) > 199 ? 199 : (NEXT);                               \
    Q = a_glob[(size_t)(r0 + nr_) * 64 + lane];                                \
    const float* ap_ = ab[t_ & 1];                                             \
    float r0a = bir, r1a = 0.f, z0a = biz, z1a = 0.f, n0a = bin_, n1a = 0.f;   \
    _Pragma("unroll") for (int k = 0; k < 64; k += 4) {                        \
      float4 av = *(const float4*)(ap_ + k);                                   \
      r0a = fmaf(wir[k], av.x, r0a);  r1a = fmaf(wir[k + 1], av.y, r1a);       \
      r0a = fmaf(wir[k + 2], av.z, r0a); r1a = fmaf(wir[k + 3], av.w, r1a);    \
      z0a = fmaf(wiz[k], av.x, z0a);  z1a = fmaf(wiz[k + 1], av.y, z1a);       \
      z0a = fmaf(wiz[k + 2], av.z, z0a); z1a = fmaf(wiz[k + 3], av.w, z1a);    \
      n0a = fmaf(win_[k], av.x, n0a); n1a = fmaf(win_[k + 1], av.y, n1a);      \
      n0a = fmaf(win_[k + 2], av.z, n0a); n1a = fmaf(win_[k + 3], av.w, n1a);  \
    }                                                                          \
    float* gp_ = gi_out + (size_t)(r0 + t_) * 192;                             \
    gp_[lane] = r0a + r1a;                                                     \
    gp_[64 + lane] = z0a + z1a;                                                \
    gp_[128 + lane] = n0a + n1a;                                               \
  }

  #pragma unroll 1
  for (int i = 0; i < 200; i += 2) {
    GI_BODY(i + 0, qA, i + 3)
    GI_BODY(i + 1, qB, i + 4)
  }
#undef GI_BODY
}

// -------- gru3_k: 1 wave per sequence, no barriers. gh+gates+fc2+argmax ------
__global__ __launch_bounds__(64, 2)
void gru3_k(const float* __restrict__ gi_glob,
            const float* __restrict__ Whh, const float* __restrict__ bhh,
            const float* __restrict__ W2, const float* __restrict__ b2,
            float* __restrict__ out) {
  __shared__ float hs[64];
  __shared__ float W2s[16 * 68];
  const int lane = threadIdx.x;

  // single-wave block: LDS ops are wave-ordered, no __syncthreads needed
  #pragma unroll
  for (int i = 0; i < 16; ++i) {
    int idx = i * 64 + lane;                  // 1024 = 16*64 elements
    W2s[(idx >> 6) * 68 + (idx & 63)] = W2[idx];
  }

  float whr[64], whz[64], whn[64];
  #pragma unroll
  for (int k = 0; k < 64; k += 4) {
    *(float4*)&whr[k] = *(const float4*)(Whh + (size_t)lane * 64 + k);
    *(float4*)&whz[k] = *(const float4*)(Whh + (size_t)(64 + lane) * 64 + k);
    *(float4*)&whn[k] = *(const float4*)(Whh + (size_t)(128 + lane) * 64 + k);
  }
  const float bhr = bhh[lane], bhz = bhh[64 + lane], bhn = bhh[128 + lane];
  const int m = lane & 15, qt = lane >> 4;
  const float b2r = b2[m];

  const int s = blockIdx.x;              // sequence = b*8 + n
  const int b = s >> 3, n = s & 7;
  const size_t rbase = (size_t)b * 1600 + n;   // r(t) = rbase + 8t

  float* outq  = out;
  float* outmv = out + (size_t)kRows * 16;
  float* outma = outmv + kRows;

  hs[lane] = 0.f;
  float h = 0.f;

  const float* gp0 = gi_glob + rbase * 192;
  float gA0 = gp0[lane], gA1 = gp0[64 + lane], gA2 = gp0[128 + lane];
  const float* gp1 = gi_glob + (rbase + 8) * 192;
  float gB0 = gp1[lane], gB1 = gp1[64 + lane], gB2 = gp1[128 + lane];

#define GRU_STEP(T, G0, G1, G2, TN)                                            \
  {                                                                            \
    const int t_ = (T);                                                        \
    const size_t r_ = rbase + (size_t)t_ * 8;                                  \
    float hr0 = bhr, hr1 = 0.f, hz0 = bhz, hz1 = 0.f, hn0 = bhn, hn1 = 0.f;    \
    _Pragma("unroll") for (int k = 0; k < 64; k += 4) {                        \
      float4 hp = *(const float4*)(hs + k);                                    \
      hr0 = fmaf(whr[k], hp.x, hr0);  hr1 = fmaf(whr[k + 1], hp.y, hr1);       \
      hr0 = fmaf(whr[k + 2], hp.z, hr0); hr1 = fmaf(whr[k + 3], hp.w, hr1);    \
      hz0 = fmaf(whz[k], hp.x, hz0);  hz1 = fmaf(whz[k + 1], hp.y, hz1);       \
      hz0 = fmaf(whz[k + 2], hp.z, hz0); hz1 = fmaf(whz[k + 3], hp.w, hz1);    \
      hn0 = fmaf(whn[k], hp.x, hn0);  hn1 = fmaf(whn[k + 1], hp.y, hn1);       \
      hn0 = fmaf(whn[k + 2], hp.z, hn0); hn1 = fmaf(whn[k + 3], hp.w, hn1);    \
    }                                                                          \
    const float rg = 1.f / (1.f + __expf(-((G0) + hr0 + hr1)));                \
    const float zg = 1.f / (1.f + __expf(-((G1) + hz0 + hz1)));                \
    const float e2 = __expf(2.f * ((G2) + rg * (hn0 + hn1)));                  \
    const float ng = 1.f - 2.f / (e2 + 1.f);                                   \
    h = (1.f - zg) * ng + zg * h;                                              \
    hs[lane] = h;                                                              \
    const int tn_ = (TN) > 199 ? 199 : (TN);                                   \
    const float* gp_ = gi_glob + (rbase + (size_t)tn_ * 8) * 192;              \
    G0 = gp_[lane]; G1 = gp_[64 + lane]; G2 = gp_[128 + lane];                 \
    float q0 = 0.f, q1 = 0.f;                                                  \
    _Pragma("unroll") for (int j = 0; j < 16; j += 4) {                        \
      float4 hp = *(const float4*)(hs + qt * 16 + j);                          \
      float4 wp = *(const float4*)(W2s + m * 68 + qt * 16 + j);                \
      q0 = fmaf(wp.x, hp.x, q0); q1 = fmaf(wp.y, hp.y, q1);                    \
      q0 = fmaf(wp.z, hp.z, q0); q1 = fmaf(wp.w, hp.w, q1);                    \
    }                                                                          \
    float q = q0 + q1;                                                         \
    q += __shfl_xor(q, 16);                                                    \
    q += __shfl_xor(q, 32);                                                    \
    q += b2r;                                                                  \
    if (lane < 16) outq[r_ * 16 + m] = q;                                      \
    float bv = q; int bi = m;                                                  \
    _Pragma("unroll") for (int d = 1; d < 16; d <<= 1) {                       \
      float ov = __shfl_xor(bv, d, 16);                                        \
      int oi = __shfl_xor(bi, d, 16);                                          \
      if (ov > bv || (ov == bv && oi < bi)) { bv = ov; bi = oi; }              \
    }                                                                          \
    if (lane == 0) { outmv[r_] = bv; outma[r_] = (float)bi; }                  \
  }

  #pragma unroll 1
  for (int t = 0; t < 200; t += 2) {
    GRU_STEP(t, gA0, gA1, gA2, t + 2)
    GRU_STEP(t + 1, gB0, gB1, gB2, t + 3)
  }
#undef GRU_STEP
}

// ---------------- R1 fallback (no/small workspace) ---------------------------
namespace fb {
constexpr int kW1Pitch = 137, kHPitch = 65;
constexpr int OFF_W1 = 0;
constexpr int OFF_WIH = OFF_W1 + 64 * kW1Pitch;
constexpr int OFF_WHH = OFF_WIH + 192 * kHPitch;
constexpr int OFF_W2 = OFF_WHH + 192 * kHPitch;
constexpr int OFF_B1 = OFF_W2 + 16 * kHPitch;
constexpr int OFF_BIH = OFF_B1 + 64;
constexpr int OFF_BHH = OFF_BIH + 192;
constexpr int OFF_B2 = OFF_BHH + 192;
constexpr int LDS_FLOATS = OFF_B2 + 16;
}

__device__ __forceinline__ float bcastf(float v, int l) {
  return __int_as_float(__builtin_amdgcn_readlane(__float_as_int(v), l));
}

__global__ __launch_bounds__(512, 1)
void drqn_fused(const float* __restrict__ obs, const int* __restrict__ agent,
                const float* __restrict__ W1, const float* __restrict__ b1,
                const float* __restrict__ Wih, const float* __restrict__ Whh,
                const float* __restrict__ bih, const float* __restrict__ bhh,
                const float* __restrict__ W2, const float* __restrict__ b2,
                float* __restrict__ out) {
  using namespace fb;
  extern __shared__ float lds[];
  float* W1s = lds + OFF_W1; float* Wihs = lds + OFF_WIH;
  float* Whhs = lds + OFF_WHH; float* W2s = lds + OFF_W2;
  float* b1s = lds + OFF_B1; float* bihs = lds + OFF_BIH;
  float* bhhs = lds + OFF_BHH; float* b2s = lds + OFF_B2;
  const int tid = threadIdx.x;
  for (int i = tid; i < 64 * 136; i += 512) { int r = i / 136, c = i - r * 136; W1s[r * kW1Pitch + c] = W1[i]; }
  for (int i = tid; i < 192 * 64; i += 512) { int r = i >> 6, c = i & 63; Wihs[r * kHPitch + c] = Wih[i]; }
  for (int i = tid; i < 192 * 64; i += 512) { int r = i >> 6, c = i & 63; Whhs[r * kHPitch + c] = Whh[i]; }
  for (int i = tid; i < 16 * 64; i += 512) { int r = i >> 6, c = i & 63; W2s[r * kHPitch + c] = W2[i]; }
  if (tid < 64) b1s[tid] = b1[tid];
  if (tid < 192) bihs[tid] = bih[tid];
  if (tid < 192) bhhs[tid] = bhh[tid];
  if (tid < 16) b2s[tid] = b2[tid];
  __syncthreads();
  const int wave = tid >> 6, lane = tid & 63;
  const int s = blockIdx.x * 8 + wave;
  const int b = s >> 3, n = s & 7;
  const int acol = 128 + agent[n];
  const float* obase = obs + (((size_t)b * kT) * kN + n) * kObs;
  const size_t qbase = (((size_t)b * kT) * kN + n) * kOut;
  const size_t mbase = ((size_t)b * kT) * kN + n;
  float* outq = out;
  float* outmv = out + (size_t)kB * kT * kN * kOut;
  float* outma = outmv + (size_t)kB * kT * kN;
  float h = 0.f;
  float xa = obase[lane], xb = obase[64 + lane];
  #pragma unroll 1
  for (int t = 0; t < kT; ++t) {
    float xan = 0.f, xbn = 0.f;
    if (t + 1 < kT) { const float* p = obase + (size_t)(t + 1) * kN * kObs; xan = p[lane]; xbn = p[64 + lane]; }
    float acc = b1s[lane] + W1s[lane * kW1Pitch + acol];
    #pragma unroll
    for (int k = 0; k < 64; ++k) acc += W1s[lane * kW1Pitch + k] * bcastf(xa, k);
    #pragma unroll
    for (int k = 0; k < 64; ++k) acc += W1s[lane * kW1Pitch + 64 + k] * bcastf(xb, k);
    float a = fmaxf(acc, 0.f);
    float air = bihs[lane], aiz = bihs[64 + lane], ain = bihs[128 + lane];
    #pragma unroll
    for (int k = 0; k < 64; ++k) {
      float sa = bcastf(a, k);
      air += Wihs[lane * kHPitch + k] * sa;
      aiz += Wihs[(64 + lane) * kHPitch + k] * sa;
      ain += Wihs[(128 + lane) * kHPitch + k] * sa;
    }
    float ghr = bhhs[lane], ghz = bhhs[64 + lane], ghn = bhhs[128 + lane];
    #pragma unroll
    for (int k = 0; k < 64; ++k) {
      float sh = bcastf(h, k);
      ghr += Whhs[lane * kHPitch + k] * sh;
      ghz += Whhs[(64 + lane) * kHPitch + k] * sh;
      ghn += Whhs[(128 + lane) * kHPitch + k] * sh;
    }
    float rg = 1.f / (1.f + expf(-(air + ghr)));
    float zg = 1.f / (1.f + expf(-(aiz + ghz)));
    float ng = tanhf(ain + rg * ghn);
    h = (1.f - zg) * ng + zg * h;
    const int m = lane & 15;
    float q = b2s[m];
    #pragma unroll
    for (int k = 0; k < 64; ++k) q += W2s[m * kHPitch + k] * bcastf(h, k);
    if (lane < 16) outq[qbase + (size_t)t * kN * kOut + m] = q;
    float bv = q; int bi = m;
    #pragma unroll
    for (int d = 1; d < 16; d <<= 1) {
      float ov = __shfl_xor(bv, d, 16);
      int oi = __shfl_xor(bi, d, 16);
      if (ov > bv || (ov == bv && oi < bi)) { bv = ov; bi = oi; }
    }
    if (lane == 0) { outmv[mbase + (size_t)t * kN] = bv; outma[mbase + (size_t)t * kN] = (float)bi; }
    xa = xan; xb = xbn;
  }
}

extern "C" void kernel_launch(void* const* d_in, const int* in_sizes, int n_in,
                              void* d_out, int out_size, void* d_ws, size_t ws_size,
                              hipStream_t stream) {
  const float* obs  = (const float*)d_in[0];
  const int* agent  = (const int*)d_in[1];
  const float* W1   = (const float*)d_in[2];
  const float* b1   = (const float*)d_in[3];
  const float* Wih  = (const float*)d_in[4];
  const float* Whh  = (const float*)d_in[5];
  const float* bih  = (const float*)d_in[6];
  const float* bhh  = (const float*)d_in[7];
  const float* W2   = (const float*)d_in[8];
  const float* b2   = (const float*)d_in[9];
  float* out = (float*)d_out;

  if (ws_size >= kABytes + kGiBytes) {
    float* a_buf  = (float*)d_ws;
    float* gi_buf = (float*)((char*)d_ws + kABytes);
    fc1_k<<<dim3(1024), dim3(256), 0, stream>>>(obs, agent, W1, b1, a_buf);
    gi_k<<<dim3(512), dim3(256), 0, stream>>>(a_buf, Wih, bih, gi_buf);
    gru3_k<<<dim3(2048), dim3(64), 0, stream>>>(gi_buf, Whh, bhh, W2, b2, out);
  } else {
    (void)hipFuncSetAttribute((const void*)drqn_fused,
                              hipFuncAttributeMaxDynamicSharedMemorySize,
                              fb::LDS_FLOATS * 4);
    drqn_fused<<<dim3(256), dim3(512), fb::LDS_FLOATS * 4, stream>>>(
        obs, agent, W1, b1, Wih, Whh, bih, bhh, W2, b2, out);
  }
}

// Round 8
// 1052.304 us; speedup vs baseline: 1.8442x; 1.8442x over previous
//
#include <hip/hip_runtime.h>

// MultiAgentDRQN R8. R5-R7 all failed on fc1 the same way: 128 weight
// floats/lane is ON the register-pressure boundary (spill or remat every
// time). Structural fix: split-K fc1.
//   fc1_k : 2 waves per row-engine. Lane l of wave-half p holds
//           W1[l][p*64..p*64+63] (64 VGPRs). Each wave stages/consumes its
//           own x-half (wave-local, no cross-wave x dep). Halves combine via
//           double-buffered LDS partials -> ONE barrier per row. One-hot col
//           + b1 folded by finishing wave. ~92 instr/row/lane, VGPR ~90.
//   gi_k  : unchanged (192 wt regs/lane, distance-3 prefetch).
//   gru3_k: unchanged (192 wt regs + W2 in LDS, no barriers).
// All fp32 (argmax-flip safety). Fallback: R1 fused kernel if ws too small.

namespace {
constexpr int kB = 256, kT = 200, kN = 8, kObs = 128, kH = 64, kOut = 16;
constexpr int kRows = kB * kT * kN;                  // 409600
constexpr size_t kABytes  = (size_t)kRows * 64 * 4;  // 100 MB
constexpr size_t kGiBytes = (size_t)kRows * 192 * 4; // 300 MB
}

// ------- fc1_k: a[r][64] = relu(x_r . W1^T + b1), split-K 2 waves/row --------
__global__ __launch_bounds__(256, 2)
void fc1_k(const float* __restrict__ obs, const int* __restrict__ agent,
           const float* __restrict__ W1, const float* __restrict__ b1,
           float* __restrict__ a_out) {
  __shared__ float xs[2][2][128];   // [engine][buf][k]
  __shared__ float ps[2][2][64];    // [engine][buf][out] partial sums
  __shared__ float ohs[512];        // ohs[n*64+l] = W1[l][128+agent[n]]
  const int tid = threadIdx.x, lane = tid & 63, w = tid >> 6;
  const int e = w >> 1, p = w & 1;  // engine, k-half

  for (int i = tid; i < 512; i += 256) {
    int n = i >> 6, l = i & 63;
    ohs[i] = W1[(size_t)l * 136 + 128 + agent[n]];
  }

  // lane's weights: W1[lane][p*64 + j], j = 0..63  (16 float4 = 64 VGPRs)
  float4 wv[16];
  #pragma unroll
  for (int k = 0; k < 16; ++k)
    wv[k] = *(const float4*)(W1 + (size_t)lane * 136 + p * 64 + k * 4);
  const float b1r = b1[lane];       // used by finishing wave (p==1)

  constexpr int ROWS = 100;         // 4096 engines x 100 rows = 409600
  const int eng = blockIdx.x * 2 + e;
  const int r0 = eng * ROWS;
  const int et = p * 64 + lane;     // engine-local staging index [0,128)

  // prologue: stage row 0 (own half), load row 1 into register
  xs[e][0][et] = obs[(size_t)r0 * 128 + et];
  float xq = obs[(size_t)(r0 + 1) * 128 + et];
  __syncthreads();                  // covers ohs + row-0 staging

  #pragma unroll 1
  for (int i = 0; i < ROWS; ++i) {
    const int r = r0 + i;
    // store row i+1 (reg) into other buffer; start load of row i+2.
    // each wave stages exactly the half it consumes -> wave-local ordering.
    if (i + 1 < ROWS) xs[e][(i + 1) & 1][et] = xq;
    const int nr = (i + 2 < ROWS) ? (r0 + i + 2) : (r0 + ROWS - 1);
    xq = obs[(size_t)nr * 128 + et];

    const float* xb = xs[e][i & 1] + p * 64;
    float a0 = 0.f, a1 = 0.f, a2 = 0.f, a3 = 0.f;
    #pragma unroll
    for (int k = 0; k < 16; ++k) {
      float4 xp = *(const float4*)(xb + k * 4);   // same-addr broadcast read
      a0 = fmaf(wv[k].x, xp.x, a0);
      a1 = fmaf(wv[k].y, xp.y, a1);
      a2 = fmaf(wv[k].z, xp.z, a2);
      a3 = fmaf(wv[k].w, xp.w, a3);
    }
    const float part = (a0 + a1) + (a2 + a3);
    if (p == 0) ps[e][i & 1][lane] = part;
    __syncthreads();                // ps(i) visible; dbuf protects i+2 reuse
    if (p == 1) {
      float av = part + ps[e][i & 1][lane] + b1r + ohs[(r & 7) * 64 + lane];
      a_out[(size_t)r * 64 + lane] = fmaxf(av, 0.f);
    }
  }
}

// ---------------- gi_k: gi[r][192] = Wih . a_r + bih -------------------------
__global__ __launch_bounds__(256, 2)
void gi_k(const float* __restrict__ a_glob, const float* __restrict__ Wih,
          const float* __restrict__ bih, float* __restrict__ gi_out) {
  __shared__ float as_[4][2][64];
  const int tid = threadIdx.x, lane = tid & 63, w = tid >> 6;

  float wir[64], wiz[64], win_[64];
  #pragma unroll
  for (int k = 0; k < 64; k += 4) {
    *(float4*)&wir[k]  = *(const float4*)(Wih + (size_t)lane * 64 + k);
    *(float4*)&wiz[k]  = *(const float4*)(Wih + (size_t)(64 + lane) * 64 + k);
    *(float4*)&win_[k] = *(const float4*)(Wih + (size_t)(128 + lane) * 64 + k);
  }
  const float bir = bih[lane], biz = bih[64 + lane], bin_ = bih[128 + lane];

  const int gwave = blockIdx.x * 4 + w;   // 2048 waves x 200 rows
  const int r0 = gwave * 200;
  float (*ab)[64] = as_[w];

  ab[0][lane] = a_glob[(size_t)r0 * 64 + lane];
  float qA = a_glob[(size_t)(r0 + 1) * 64 + lane];
  float qB = a_glob[(size_t)(r0 + 2) * 64 + lane];

#define GI_BODY(T, Q, NEXT)                                                    \
  {                                                                            \
    const int t_ = (T);                                                        \
    if (t_ < 199) ab[(t_ + 1) & 1][lane] = Q;                                  \
    const int nr_ = (NEXT) > 199 ? 199 : (NEXT);                               \
    Q = a_glob[(size_t)(r0 + nr_) * 64 + lane];                                \
    const float* ap_ = ab[t_ & 1];                                             \
    float r0a = bir, r1a = 0.f, z0a = biz, z1a = 0.f, n0a = bin_, n1a = 0.f;   \
    _Pragma("unroll") for (int k = 0; k < 64; k += 4) {                        \
      float4 av = *(const float4*)(ap_ + k);                                   \
      r0a = fmaf(wir[k], av.x, r0a);  r1a = fmaf(wir[k + 1], av.y, r1a);       \
      r0a = fmaf(wir[k + 2], av.z, r0a); r1a = fmaf(wir[k + 3], av.w, r1a);    \
      z0a = fmaf(wiz[k], av.x, z0a);  z1a = fmaf(wiz[k + 1], av.y, z1a);       \
      z0a = fmaf(wiz[k + 2], av.z, z0a); z1a = fmaf(wiz[k + 3], av.w, z1a);    \
      n0a = fmaf(win_[k], av.x, n0a); n1a = fmaf(win_[k + 1], av.y, n1a);      \
      n0a = fmaf(win_[k + 2], av.z, n0a); n1a = fmaf(win_[k + 3], av.w, n1a);  \
    }                                                                          \
    float* gp_ = gi_out + (size_t)(r0 + t_) * 192;                             \
    gp_[lane] = r0a + r1a;                                                     \
    gp_[64 + lane] = z0a + z1a;                                                \
    gp_[128 + lane] = n0a + n1a;                                               \
  }

  #pragma unroll 1
  for (int i = 0; i < 200; i += 2) {
    GI_BODY(i + 0, qA, i + 3)
    GI_BODY(i + 1, qB, i + 4)
  }
#undef GI_BODY
}

// -------- gru3_k: 1 wave per sequence, no barriers. gh+gates+fc2+argmax ------
__global__ __launch_bounds__(64, 2)
void gru3_k(const float* __restrict__ gi_glob,
            const float* __restrict__ Whh, const float* __restrict__ bhh,
            const float* __restrict__ W2, const float* __restrict__ b2,
            float* __restrict__ out) {
  __shared__ float hs[64];
  __shared__ float W2s[16 * 68];
  const int lane = threadIdx.x;

  // single-wave block: LDS ops are wave-ordered, no __syncthreads needed
  #pragma unroll
  for (int i = 0; i < 16; ++i) {
    int idx = i * 64 + lane;                  // 1024 = 16*64 elements
    W2s[(idx >> 6) * 68 + (idx & 63)] = W2[idx];
  }

  float whr[64], whz[64], whn[64];
  #pragma unroll
  for (int k = 0; k < 64; k += 4) {
    *(float4*)&whr[k] = *(const float4*)(Whh + (size_t)lane * 64 + k);
    *(float4*)&whz[k] = *(const float4*)(Whh + (size_t)(64 + lane) * 64 + k);
    *(float4*)&whn[k] = *(const float4*)(Whh + (size_t)(128 + lane) * 64 + k);
  }
  const float bhr = bhh[lane], bhz = bhh[64 + lane], bhn = bhh[128 + lane];
  const int m = lane & 15, qt = lane >> 4;
  const float b2r = b2[m];

  const int s = blockIdx.x;              // sequence = b*8 + n
  const int b = s >> 3, n = s & 7;
  const size_t rbase = (size_t)b * 1600 + n;   // r(t) = rbase + 8t

  float* outq  = out;
  float* outmv = out + (size_t)kRows * 16;
  float* outma = outmv + kRows;

  hs[lane] = 0.f;
  float h = 0.f;

  const float* gp0 = gi_glob + rbase * 192;
  float gA0 = gp0[lane], gA1 = gp0[64 + lane], gA2 = gp0[128 + lane];
  const float* gp1 = gi_glob + (rbase + 8) * 192;
  float gB0 = gp1[lane], gB1 = gp1[64 + lane], gB2 = gp1[128 + lane];

#define GRU_STEP(T, G0, G1, G2, TN)                                            \
  {                                                                            \
    const int t_ = (T);                                                        \
    const size_t r_ = rbase + (size_t)t_ * 8;                                  \
    float hr0 = bhr, hr1 = 0.f, hz0 = bhz, hz1 = 0.f, hn0 = bhn, hn1 = 0.f;    \
    _Pragma("unroll") for (int k = 0; k < 64; k += 4) {                        \
      float4 hp = *(const float4*)(hs + k);                                    \
      hr0 = fmaf(whr[k], hp.x, hr0);  hr1 = fmaf(whr[k + 1], hp.y, hr1);       \
      hr0 = fmaf(whr[k + 2], hp.z, hr0); hr1 = fmaf(whr[k + 3], hp.w, hr1);    \
      hz0 = fmaf(whz[k], hp.x, hz0);  hz1 = fmaf(whz[k + 1], hp.y, hz1);       \
      hz0 = fmaf(whz[k + 2], hp.z, hz0); hz1 = fmaf(whz[k + 3], hp.w, hz1);    \
      hn0 = fmaf(whn[k], hp.x, hn0);  hn1 = fmaf(whn[k + 1], hp.y, hn1);       \
      hn0 = fmaf(whn[k + 2], hp.z, hn0); hn1 = fmaf(whn[k + 3], hp.w, hn1);    \
    }                                                                          \
    const float rg = 1.f / (1.f + __expf(-((G0) + hr0 + hr1)));                \
    const float zg = 1.f / (1.f + __expf(-((G1) + hz0 + hz1)));                \
    const float e2 = __expf(2.f * ((G2) + rg * (hn0 + hn1)));                  \
    const float ng = 1.f - 2.f / (e2 + 1.f);                                   \
    h = (1.f - zg) * ng + zg * h;                                              \
    hs[lane] = h;                                                              \
    const int tn_ = (TN) > 199 ? 199 : (TN);                                   \
    const float* gp_ = gi_glob + (rbase + (size_t)tn_ * 8) * 192;              \
    G0 = gp_[lane]; G1 = gp_[64 + lane]; G2 = gp_[128 + lane];                 \
    float q0 = 0.f, q1 = 0.f;                                                  \
    _Pragma("unroll") for (int j = 0; j < 16; j += 4) {                        \
      float4 hp = *(const float4*)(hs + qt * 16 + j);                          \
      float4 wp = *(const float4*)(W2s + m * 68 + qt * 16 + j);                \
      q0 = fmaf(wp.x, hp.x, q0); q1 = fmaf(wp.y, hp.y, q1);                    \
      q0 = fmaf(wp.z, hp.z, q0); q1 = fmaf(wp.w, hp.w, q1);                    \
    }                                                                          \
    float q = q0 + q1;                                                         \
    q += __shfl_xor(q, 16);                                                    \
    q += __shfl_xor(q, 32);                                                    \
    q += b2r;                                                                  \
    if (lane < 16) outq[r_ * 16 + m] = q;                                      \
    float bv = q; int bi = m;                                                  \
    _Pragma("unroll") for (int d = 1; d < 16; d <<= 1) {                       \
      float ov = __shfl_xor(bv, d, 16);                                        \
      int oi = __shfl_xor(bi, d, 16);                                          \
      if (ov > bv || (ov == bv && oi < bi)) { bv = ov; bi = oi; }              \
    }                                                                          \
    if (lane == 0) { outmv[r_] = bv; outma[r_] = (float)bi; }                  \
  }

  #pragma unroll 1
  for (int t = 0; t < 200; t += 2) {
    GRU_STEP(t, gA0, gA1, gA2, t + 2)
    GRU_STEP(t + 1, gB0, gB1, gB2, t + 3)
  }
#undef GRU_STEP
}

// ---------------- R1 fallback (no/small workspace) ---------------------------
namespace fb {
constexpr int kW1Pitch = 137, kHPitch = 65;
constexpr int OFF_W1 = 0;
constexpr int OFF_WIH = OFF_W1 + 64 * kW1Pitch;
constexpr int OFF_WHH = OFF_WIH + 192 * kHPitch;
constexpr int OFF_W2 = OFF_WHH + 192 * kHPitch;
constexpr int OFF_B1 = OFF_W2 + 16 * kHPitch;
constexpr int OFF_BIH = OFF_B1 + 64;
constexpr int OFF_BHH = OFF_BIH + 192;
constexpr int OFF_B2 = OFF_BHH + 192;
constexpr int LDS_FLOATS = OFF_B2 + 16;
}

__device__ __forceinline__ float bcastf(float v, int l) {
  return __int_as_float(__builtin_amdgcn_readlane(__float_as_int(v), l));
}

__global__ __launch_bounds__(512, 1)
void drqn_fused(const float* __restrict__ obs, const int* __restrict__ agent,
                const float* __restrict__ W1, const float* __restrict__ b1,
                const float* __restrict__ Wih, const float* __restrict__ Whh,
                const float* __restrict__ bih, const float* __restrict__ bhh,
                const float* __restrict__ W2, const float* __restrict__ b2,
                float* __restrict__ out) {
  using namespace fb;
  extern __shared__ float lds[];
  float* W1s = lds + OFF_W1; float* Wihs = lds + OFF_WIH;
  float* Whhs = lds + OFF_WHH; float* W2s = lds + OFF_W2;
  float* b1s = lds + OFF_B1; float* bihs = lds + OFF_BIH;
  float* bhhs = lds + OFF_BHH; float* b2s = lds + OFF_B2;
  const int tid = threadIdx.x;
  for (int i = tid; i < 64 * 136; i += 512) { int r = i / 136, c = i - r * 136; W1s[r * kW1Pitch + c] = W1[i]; }
  for (int i = tid; i < 192 * 64; i += 512) { int r = i >> 6, c = i & 63; Wihs[r * kHPitch + c] = Wih[i]; }
  for (int i = tid; i < 192 * 64; i += 512) { int r = i >> 6, c = i & 63; Whhs[r * kHPitch + c] = Whh[i]; }
  for (int i = tid; i < 16 * 64; i += 512) { int r = i >> 6, c = i & 63; W2s[r * kHPitch + c] = W2[i]; }
  if (tid < 64) b1s[tid] = b1[tid];
  if (tid < 192) bihs[tid] = bih[tid];
  if (tid < 192) bhhs[tid] = bhh[tid];
  if (tid < 16) b2s[tid] = b2[tid];
  __syncthreads();
  const int wave = tid >> 6, lane = tid & 63;
  const int s = blockIdx.x * 8 + wave;
  const int b = s >> 3, n = s & 7;
  const int acol = 128 + agent[n];
  const float* obase = obs + (((size_t)b * kT) * kN + n) * kObs;
  const size_t qbase = (((size_t)b * kT) * kN + n) * kOut;
  const size_t mbase = ((size_t)b * kT) * kN + n;
  float* outq = out;
  float* outmv = out + (size_t)kB * kT * kN * kOut;
  float* outma = outmv + (size_t)kB * kT * kN;
  float h = 0.f;
  float xa = obase[lane], xb = obase[64 + lane];
  #pragma unroll 1
  for (int t = 0; t < kT; ++t) {
    float xan = 0.f, xbn = 0.f;
    if (t + 1 < kT) { const float* p = obase + (size_t)(t + 1) * kN * kObs; xan = p[lane]; xbn = p[64 + lane]; }
    float acc = b1s[lane] + W1s[lane * kW1Pitch + acol];
    #pragma unroll
    for (int k = 0; k < 64; ++k) acc += W1s[lane * kW1Pitch + k] * bcastf(xa, k);
    #pragma unroll
    for (int k = 0; k < 64; ++k) acc += W1s[lane * kW1Pitch + 64 + k] * bcastf(xb, k);
    float a = fmaxf(acc, 0.f);
    float air = bihs[lane], aiz = bihs[64 + lane], ain = bihs[128 + lane];
    #pragma unroll
    for (int k = 0; k < 64; ++k) {
      float sa = bcastf(a, k);
      air += Wihs[lane * kHPitch + k] * sa;
      aiz += Wihs[(64 + lane) * kHPitch + k] * sa;
      ain += Wihs[(128 + lane) * kHPitch + k] * sa;
    }
    float ghr = bhhs[lane], ghz = bhhs[64 + lane], ghn = bhhs[128 + lane];
    #pragma unroll
    for (int k = 0; k < 64; ++k) {
      float sh = bcastf(h, k);
      ghr += Whhs[lane * kHPitch + k] * sh;
      ghz += Whhs[(64 + lane) * kHPitch + k] * sh;
      ghn += Whhs[(128 + lane) * kHPitch + k] * sh;
    }
    float rg = 1.f / (1.f + expf(-(air + ghr)));
    float zg = 1.f / (1.f + expf(-(aiz + ghz)));
    float ng = tanhf(ain + rg * ghn);
    h = (1.f - zg) * ng + zg * h;
    const int m = lane & 15;
    float q = b2s[m];
    #pragma unroll
    for (int k = 0; k < 64; ++k) q += W2s[m * kHPitch + k] * bcastf(h, k);
    if (lane < 16) outq[qbase + (size_t)t * kN * kOut + m] = q;
    float bv = q; int bi = m;
    #pragma unroll
    for (int d = 1; d < 16; d <<= 1) {
      float ov = __shfl_xor(bv, d, 16);
      int oi = __shfl_xor(bi, d, 16);
      if (ov > bv || (ov == bv && oi < bi)) { bv = ov; bi = oi; }
    }
    if (lane == 0) { outmv[mbase + (size_t)t * kN] = bv; outma[mbase + (size_t)t * kN] = (float)bi; }
    xa = xan; xb = xbn;
  }
}

extern "C" void kernel_launch(void* const* d_in, const int* in_sizes, int n_in,
                              void* d_out, int out_size, void* d_ws, size_t ws_size,
                              hipStream_t stream) {
  const float* obs  = (const float*)d_in[0];
  const int* agent  = (const int*)d_in[1];
  const float* W1   = (const float*)d_in[2];
  const float* b1   = (const float*)d_in[3];
  const float* Wih  = (const float*)d_in[4];
  const float* Whh  = (const float*)d_in[5];
  const float* bih  = (const float*)d_in[6];
  const float* bhh  = (const float*)d_in[7];
  const float* W2   = (const float*)d_in[8];
  const float* b2   = (const float*)d_in[9];
  float* out = (float*)d_out;

  if (ws_size >= kABytes + kGiBytes) {
    float* a_buf  = (float*)d_ws;
    float* gi_buf = (float*)((char*)d_ws + kABytes);
    fc1_k<<<dim3(2048), dim3(256), 0, stream>>>(obs, agent, W1, b1, a_buf);
    gi_k<<<dim3(512), dim3(256), 0, stream>>>(a_buf, Wih, bih, gi_buf);
    gru3_k<<<dim3(2048), dim3(64), 0, stream>>>(gi_buf, Whh, bhh, W2, b2, out);
  } else {
    (void)hipFuncSetAttribute((const void*)drqn_fused,
                              hipFuncAttributeMaxDynamicSharedMemorySize,
                              fb::LDS_FLOATS * 4);
    drqn_fused<<<dim3(256), dim3(512), fb::LDS_FLOATS * 4, stream>>>(
        obs, agent, W1, b1, Wih, Whh, bih, bhh, W2, b2, out);
  }
}

// Round 9
// 608.957 us; speedup vs baseline: 3.1869x; 1.7280x over previous
//
#include <hip/hip_runtime.h>

// MultiAgentDRQN R9. R8 post-mortem: gru3_k at VGPR=128 < 192 weight floats ->
// compiler spilled Whh to scratch (754us, FETCH 158MB). Cause: R7's "W2 to
// LDS" edit perturbed regalloc. Revert gru3_k EXACTLY to the R6 version
// (w2r[16] in registers, no W2s LDS). fc1 split-K (R8, works) and gi_k
// unchanged. One variable this round.
// All fp32 (argmax-flip safety). Fallback: R1 fused kernel if ws too small.

namespace {
constexpr int kB = 256, kT = 200, kN = 8, kObs = 128, kH = 64, kOut = 16;
constexpr int kRows = kB * kT * kN;                  // 409600
constexpr size_t kABytes  = (size_t)kRows * 64 * 4;  // 100 MB
constexpr size_t kGiBytes = (size_t)kRows * 192 * 4; // 300 MB
}

// ------- fc1_k: a[r][64] = relu(x_r . W1^T + b1), split-K 2 waves/row --------
__global__ __launch_bounds__(256, 2)
void fc1_k(const float* __restrict__ obs, const int* __restrict__ agent,
           const float* __restrict__ W1, const float* __restrict__ b1,
           float* __restrict__ a_out) {
  __shared__ float xs[2][2][128];   // [engine][buf][k]
  __shared__ float ps[2][2][64];    // [engine][buf][out] partial sums
  __shared__ float ohs[512];        // ohs[n*64+l] = W1[l][128+agent[n]]
  const int tid = threadIdx.x, lane = tid & 63, w = tid >> 6;
  const int e = w >> 1, p = w & 1;  // engine, k-half

  for (int i = tid; i < 512; i += 256) {
    int n = i >> 6, l = i & 63;
    ohs[i] = W1[(size_t)l * 136 + 128 + agent[n]];
  }

  // lane's weights: W1[lane][p*64 + j], j = 0..63  (16 float4 = 64 VGPRs)
  float4 wv[16];
  #pragma unroll
  for (int k = 0; k < 16; ++k)
    wv[k] = *(const float4*)(W1 + (size_t)lane * 136 + p * 64 + k * 4);
  const float b1r = b1[lane];       // used by finishing wave (p==1)

  constexpr int ROWS = 100;         // 4096 engines x 100 rows = 409600
  const int eng = blockIdx.x * 2 + e;
  const int r0 = eng * ROWS;
  const int et = p * 64 + lane;     // engine-local staging index [0,128)

  // prologue: stage row 0 (own half), load row 1 into register
  xs[e][0][et] = obs[(size_t)r0 * 128 + et];
  float xq = obs[(size_t)(r0 + 1) * 128 + et];
  __syncthreads();                  // covers ohs + row-0 staging

  #pragma unroll 1
  for (int i = 0; i < ROWS; ++i) {
    const int r = r0 + i;
    // store row i+1 (reg) into other buffer; start load of row i+2.
    if (i + 1 < ROWS) xs[e][(i + 1) & 1][et] = xq;
    const int nr = (i + 2 < ROWS) ? (r0 + i + 2) : (r0 + ROWS - 1);
    xq = obs[(size_t)nr * 128 + et];

    const float* xb = xs[e][i & 1] + p * 64;
    float a0 = 0.f, a1 = 0.f, a2 = 0.f, a3 = 0.f;
    #pragma unroll
    for (int k = 0; k < 16; ++k) {
      float4 xp = *(const float4*)(xb + k * 4);   // same-addr broadcast read
      a0 = fmaf(wv[k].x, xp.x, a0);
      a1 = fmaf(wv[k].y, xp.y, a1);
      a2 = fmaf(wv[k].z, xp.z, a2);
      a3 = fmaf(wv[k].w, xp.w, a3);
    }
    const float part = (a0 + a1) + (a2 + a3);
    if (p == 0) ps[e][i & 1][lane] = part;
    __syncthreads();                // ps(i) visible; dbuf protects i+2 reuse
    if (p == 1) {
      float av = part + ps[e][i & 1][lane] + b1r + ohs[(r & 7) * 64 + lane];
      a_out[(size_t)r * 64 + lane] = fmaxf(av, 0.f);
    }
  }
}

// ---------------- gi_k: gi[r][192] = Wih . a_r + bih -------------------------
__global__ __launch_bounds__(256, 2)
void gi_k(const float* __restrict__ a_glob, const float* __restrict__ Wih,
          const float* __restrict__ bih, float* __restrict__ gi_out) {
  __shared__ float as_[4][2][64];
  const int tid = threadIdx.x, lane = tid & 63, w = tid >> 6;

  float wir[64], wiz[64], win_[64];
  #pragma unroll
  for (int k = 0; k < 64; k += 4) {
    *(float4*)&wir[k]  = *(const float4*)(Wih + (size_t)lane * 64 + k);
    *(float4*)&wiz[k]  = *(const float4*)(Wih + (size_t)(64 + lane) * 64 + k);
    *(float4*)&win_[k] = *(const float4*)(Wih + (size_t)(128 + lane) * 64 + k);
  }
  const float bir = bih[lane], biz = bih[64 + lane], bin_ = bih[128 + lane];

  const int gwave = blockIdx.x * 4 + w;   // 2048 waves x 200 rows
  const int r0 = gwave * 200;
  float (*ab)[64] = as_[w];

  ab[0][lane] = a_glob[(size_t)r0 * 64 + lane];
  float qA = a_glob[(size_t)(r0 + 1) * 64 + lane];
  float qB = a_glob[(size_t)(r0 + 2) * 64 + lane];

#define GI_BODY(T, Q, NEXT)                                                    \
  {                                                                            \
    const int t_ = (T);                                                        \
    if (t_ < 199) ab[(t_ + 1) & 1][lane] = Q;                                  \
    const int nr_ = (NEXT) > 199 ? 199 : (NEXT);                               \
    Q = a_glob[(size_t)(r0 + nr_) * 64 + lane];                                \
    const float* ap_ = ab[t_ & 1];                                             \
    float r0a = bir, r1a = 0.f, z0a = biz, z1a = 0.f, n0a = bin_, n1a = 0.f;   \
    _Pragma("unroll") for (int k = 0; k < 64; k += 4) {                        \
      float4 av = *(const float4*)(ap_ + k);                                   \
      r0a = fmaf(wir[k], av.x, r0a);  r1a = fmaf(wir[k + 1], av.y, r1a);       \
      r0a = fmaf(wir[k + 2], av.z, r0a); r1a = fmaf(wir[k + 3], av.w, r1a);    \
      z0a = fmaf(wiz[k], av.x, z0a);  z1a = fmaf(wiz[k + 1], av.y, z1a);       \
      z0a = fmaf(wiz[k + 2], av.z, z0a); z1a = fmaf(wiz[k + 3], av.w, z1a);    \
      n0a = fmaf(win_[k], av.x, n0a); n1a = fmaf(win_[k + 1], av.y, n1a);      \
      n0a = fmaf(win_[k + 2], av.z, n0a); n1a = fmaf(win_[k + 3], av.w, n1a);  \
    }                                                                          \
    float* gp_ = gi_out + (size_t)(r0 + t_) * 192;                             \
    gp_[lane] = r0a + r1a;                                                     \
    gp_[64 + lane] = z0a + z1a;                                                \
    gp_[128 + lane] = n0a + n1a;                                               \
  }

  #pragma unroll 1
  for (int i = 0; i < 200; i += 2) {
    GI_BODY(i + 0, qA, i + 3)
    GI_BODY(i + 1, qB, i + 4)
  }
#undef GI_BODY
}

// -------- gru3_k: 1 wave per sequence, no barriers (R6 version) --------------
__global__ __launch_bounds__(64, 2)
void gru3_k(const float* __restrict__ gi_glob,
            const float* __restrict__ Whh, const float* __restrict__ bhh,
            const float* __restrict__ W2, const float* __restrict__ b2,
            float* __restrict__ out) {
  __shared__ float hs[64];
  const int lane = threadIdx.x;

  float whr[64], whz[64], whn[64];
  #pragma unroll
  for (int k = 0; k < 64; k += 4) {
    *(float4*)&whr[k] = *(const float4*)(Whh + (size_t)lane * 64 + k);
    *(float4*)&whz[k] = *(const float4*)(Whh + (size_t)(64 + lane) * 64 + k);
    *(float4*)&whn[k] = *(const float4*)(Whh + (size_t)(128 + lane) * 64 + k);
  }
  const float bhr = bhh[lane], bhz = bhh[64 + lane], bhn = bhh[128 + lane];
  const int m = lane & 15, qt = lane >> 4;
  float w2r[16];
  #pragma unroll
  for (int j = 0; j < 16; j += 4)
    *(float4*)&w2r[j] = *(const float4*)(W2 + (size_t)m * 64 + qt * 16 + j);
  const float b2r = b2[m];

  const int s = blockIdx.x;              // sequence = b*8 + n
  const int b = s >> 3, n = s & 7;
  const size_t rbase = (size_t)b * 1600 + n;   // r(t) = rbase + 8t

  float* outq  = out;
  float* outmv = out + (size_t)kRows * 16;
  float* outma = outmv + kRows;

  hs[lane] = 0.f;
  float h = 0.f;

  // prefetch gi for t=0 (slot A) and t=1 (slot B)
  const float* gp0 = gi_glob + rbase * 192;
  float gA0 = gp0[lane], gA1 = gp0[64 + lane], gA2 = gp0[128 + lane];
  const float* gp1 = gi_glob + (rbase + 8) * 192;
  float gB0 = gp1[lane], gB1 = gp1[64 + lane], gB2 = gp1[128 + lane];

#define GRU_STEP(T, G0, G1, G2, TN)                                            \
  {                                                                            \
    const int t_ = (T);                                                        \
    const size_t r_ = rbase + (size_t)t_ * 8;                                  \
    float hr0 = bhr, hr1 = 0.f, hz0 = bhz, hz1 = 0.f, hn0 = bhn, hn1 = 0.f;    \
    _Pragma("unroll") for (int k = 0; k < 64; k += 4) {                        \
      float4 hp = *(const float4*)(hs + k);                                    \
      hr0 = fmaf(whr[k], hp.x, hr0);  hr1 = fmaf(whr[k + 1], hp.y, hr1);       \
      hr0 = fmaf(whr[k + 2], hp.z, hr0); hr1 = fmaf(whr[k + 3], hp.w, hr1);    \
      hz0 = fmaf(whz[k], hp.x, hz0);  hz1 = fmaf(whz[k + 1], hp.y, hz1);       \
      hz0 = fmaf(whz[k + 2], hp.z, hz0); hz1 = fmaf(whz[k + 3], hp.w, hz1);    \
      hn0 = fmaf(whn[k], hp.x, hn0);  hn1 = fmaf(whn[k + 1], hp.y, hn1);       \
      hn0 = fmaf(whn[k + 2], hp.z, hn0); hn1 = fmaf(whn[k + 3], hp.w, hn1);    \
    }                                                                          \
    const float rg = 1.f / (1.f + __expf(-((G0) + hr0 + hr1)));                \
    const float zg = 1.f / (1.f + __expf(-((G1) + hz0 + hz1)));                \
    const float e2 = __expf(2.f * ((G2) + rg * (hn0 + hn1)));                  \
    const float ng = 1.f - 2.f / (e2 + 1.f);                                   \
    h = (1.f - zg) * ng + zg * h;                                              \
    hs[lane] = h;                                                              \
    const int tn_ = (TN) > 199 ? 199 : (TN);                                   \
    const float* gp_ = gi_glob + (rbase + (size_t)tn_ * 8) * 192;              \
    G0 = gp_[lane]; G1 = gp_[64 + lane]; G2 = gp_[128 + lane];                 \
    float q0 = 0.f, q1 = 0.f;                                                  \
    _Pragma("unroll") for (int j = 0; j < 16; j += 4) {                        \
      float4 hp = *(const float4*)(hs + qt * 16 + j);                          \
      q0 = fmaf(w2r[j], hp.x, q0);     q1 = fmaf(w2r[j + 1], hp.y, q1);        \
      q0 = fmaf(w2r[j + 2], hp.z, q0); q1 = fmaf(w2r[j + 3], hp.w, q1);        \
    }                                                                          \
    float q = q0 + q1;                                                         \
    q += __shfl_xor(q, 16);                                                    \
    q += __shfl_xor(q, 32);                                                    \
    q += b2r;                                                                  \
    if (lane < 16) outq[r_ * 16 + m] = q;                                      \
    float bv = q; int bi = m;                                                  \
    _Pragma("unroll") for (int d = 1; d < 16; d <<= 1) {                       \
      float ov = __shfl_xor(bv, d, 16);                                        \
      int oi = __shfl_xor(bi, d, 16);                                          \
      if (ov > bv || (ov == bv && oi < bi)) { bv = ov; bi = oi; }              \
    }                                                                          \
    if (lane == 0) { outmv[r_] = bv; outma[r_] = (float)bi; }                  \
  }

  #pragma unroll 1
  for (int t = 0; t < 200; t += 2) {
    GRU_STEP(t, gA0, gA1, gA2, t + 2)
    GRU_STEP(t + 1, gB0, gB1, gB2, t + 3)
  }
#undef GRU_STEP
}

// ---------------- R1 fallback (no/small workspace) ---------------------------
namespace fb {
constexpr int kW1Pitch = 137, kHPitch = 65;
constexpr int OFF_W1 = 0;
constexpr int OFF_WIH = OFF_W1 + 64 * kW1Pitch;
constexpr int OFF_WHH = OFF_WIH + 192 * kHPitch;
constexpr int OFF_W2 = OFF_WHH + 192 * kHPitch;
constexpr int OFF_B1 = OFF_W2 + 16 * kHPitch;
constexpr int OFF_BIH = OFF_B1 + 64;
constexpr int OFF_BHH = OFF_BIH + 192;
constexpr int OFF_B2 = OFF_BHH + 192;
constexpr int LDS_FLOATS = OFF_B2 + 16;
}

__device__ __forceinline__ float bcastf(float v, int l) {
  return __int_as_float(__builtin_amdgcn_readlane(__float_as_int(v), l));
}

__global__ __launch_bounds__(512, 1)
void drqn_fused(const float* __restrict__ obs, const int* __restrict__ agent,
                const float* __restrict__ W1, const float* __restrict__ b1,
                const float* __restrict__ Wih, const float* __restrict__ Whh,
                const float* __restrict__ bih, const float* __restrict__ bhh,
                const float* __restrict__ W2, const float* __restrict__ b2,
                float* __restrict__ out) {
  using namespace fb;
  extern __shared__ float lds[];
  float* W1s = lds + OFF_W1; float* Wihs = lds + OFF_WIH;
  float* Whhs = lds + OFF_WHH; float* W2s = lds + OFF_W2;
  float* b1s = lds + OFF_B1; float* bihs = lds + OFF_BIH;
  float* bhhs = lds + OFF_BHH; float* b2s = lds + OFF_B2;
  const int tid = threadIdx.x;
  for (int i = tid; i < 64 * 136; i += 512) { int r = i / 136, c = i - r * 136; W1s[r * kW1Pitch + c] = W1[i]; }
  for (int i = tid; i < 192 * 64; i += 512) { int r = i >> 6, c = i & 63; Wihs[r * kHPitch + c] = Wih[i]; }
  for (int i = tid; i < 192 * 64; i += 512) { int r = i >> 6, c = i & 63; Whhs[r * kHPitch + c] = Whh[i]; }
  for (int i = tid; i < 16 * 64; i += 512) { int r = i >> 6, c = i & 63; W2s[r * kHPitch + c] = W2[i]; }
  if (tid < 64) b1s[tid] = b1[tid];
  if (tid < 192) bihs[tid] = bih[tid];
  if (tid < 192) bhhs[tid] = bhh[tid];
  if (tid < 16) b2s[tid] = b2[tid];
  __syncthreads();
  const int wave = tid >> 6, lane = tid & 63;
  const int s = blockIdx.x * 8 + wave;
  const int b = s >> 3, n = s & 7;
  const int acol = 128 + agent[n];
  const float* obase = obs + (((size_t)b * kT) * kN + n) * kObs;
  const size_t qbase = (((size_t)b * kT) * kN + n) * kOut;
  const size_t mbase = ((size_t)b * kT) * kN + n;
  float* outq = out;
  float* outmv = out + (size_t)kB * kT * kN * kOut;
  float* outma = outmv + (size_t)kB * kT * kN;
  float h = 0.f;
  float xa = obase[lane], xb = obase[64 + lane];
  #pragma unroll 1
  for (int t = 0; t < kT; ++t) {
    float xan = 0.f, xbn = 0.f;
    if (t + 1 < kT) { const float* p = obase + (size_t)(t + 1) * kN * kObs; xan = p[lane]; xbn = p[64 + lane]; }
    float acc = b1s[lane] + W1s[lane * kW1Pitch + acol];
    #pragma unroll
    for (int k = 0; k < 64; ++k) acc += W1s[lane * kW1Pitch + k] * bcastf(xa, k);
    #pragma unroll
    for (int k = 0; k < 64; ++k) acc += W1s[lane * kW1Pitch + 64 + k] * bcastf(xb, k);
    float a = fmaxf(acc, 0.f);
    float air = bihs[lane], aiz = bihs[64 + lane], ain = bihs[128 + lane];
    #pragma unroll
    for (int k = 0; k < 64; ++k) {
      float sa = bcastf(a, k);
      air += Wihs[lane * kHPitch + k] * sa;
      aiz += Wihs[(64 + lane) * kHPitch + k] * sa;
      ain += Wihs[(128 + lane) * kHPitch + k] * sa;
    }
    float ghr = bhhs[lane], ghz = bhhs[64 + lane], ghn = bhhs[128 + lane];
    #pragma unroll
    for (int k = 0; k < 64; ++k) {
      float sh = bcastf(h, k);
      ghr += Whhs[lane * kHPitch + k] * sh;
      ghz += Whhs[(64 + lane) * kHPitch + k] * sh;
      ghn += Whhs[(128 + lane) * kHPitch + k] * sh;
    }
    float rg = 1.f / (1.f + expf(-(air + ghr)));
    float zg = 1.f / (1.f + expf(-(aiz + ghz)));
    float ng = tanhf(ain + rg * ghn);
    h = (1.f - zg) * ng + zg * h;
    const int m = lane & 15;
    float q = b2s[m];
    #pragma unroll
    for (int k = 0; k < 64; ++k) q += W2s[m * kHPitch + k] * bcastf(h, k);
    if (lane < 16) outq[qbase + (size_t)t * kN * kOut + m] = q;
    float bv = q; int bi = m;
    #pragma unroll
    for (int d = 1; d < 16; d <<= 1) {
      float ov = __shfl_xor(bv, d, 16);
      int oi = __shfl_xor(bi, d, 16);
      if (ov > bv || (ov == bv && oi < bi)) { bv = ov; bi = oi; }
    }
    if (lane == 0) { outmv[mbase + (size_t)t * kN] = bv; outma[mbase + (size_t)t * kN] = (float)bi; }
    xa = xan; xb = xbn;
  }
}

extern "C" void kernel_launch(void* const* d_in, const int* in_sizes, int n_in,
                              void* d_out, int out_size, void* d_ws, size_t ws_size,
                              hipStream_t stream) {
  const float* obs  = (const float*)d_in[0];
  const int* agent  = (const int*)d_in[1];
  const float* W1   = (const float*)d_in[2];
  const float* b1   = (const float*)d_in[3];
  const float* Wih  = (const float*)d_in[4];
  const float* Whh  = (const float*)d_in[5];
  const float* bih  = (const float*)d_in[6];
  const float* bhh  = (const float*)d_in[7];
  const float* W2   = (const float*)d_in[8];
  const float* b2   = (const float*)d_in[9];
  float* out = (float*)d_out;

  if (ws_size >= kABytes + kGiBytes) {
    float* a_buf  = (float*)d_ws;
    float* gi_buf = (float*)((char*)d_ws + kABytes);
    fc1_k<<<dim3(2048), dim3(256), 0, stream>>>(obs, agent, W1, b1, a_buf);
    gi_k<<<dim3(512), dim3(256), 0, stream>>>(a_buf, Wih, bih, gi_buf);
    gru3_k<<<dim3(2048), dim3(64), 0, stream>>>(gi_buf, Whh, bhh, W2, b2, out);
  } else {
    (void)hipFuncSetAttribute((const void*)drqn_fused,
                              hipFuncAttributeMaxDynamicSharedMemorySize,
                              fb::LDS_FLOATS * 4);
    drqn_fused<<<dim3(256), dim3(512), fb::LDS_FLOATS * 4, stream>>>(
        obs, agent, W1, b1, Wih, Whh, bih, bhh, W2, b2, out);
  }
}

// Round 10
// 595.762 us; speedup vs baseline: 3.2575x; 1.0221x over previous
//
#include <hip/hip_runtime.h>

// MultiAgentDRQN R10. R9 post-mortem: gru3_k VGPR=128 < 192 weight floats ->
// compiler sank weight loads into the loop (L1 reloads ~300cyc/step extra
// issue) chasing 4-waves/SIMD occupancy that launch_bounds(64,2) PERMITS.
// Single change: gru3_k -> __launch_bounds__(64, 1): budget 512 VGPRs, all
// weights stay resident (~240 used); 240<=256 so HW still co-schedules
// 2 waves/SIMD. fc1_k (split-K) / gi_k unchanged.
// All fp32 (argmax-flip safety). Fallback: R1 fused kernel if ws too small.

namespace {
constexpr int kB = 256, kT = 200, kN = 8, kObs = 128, kH = 64, kOut = 16;
constexpr int kRows = kB * kT * kN;                  // 409600
constexpr size_t kABytes  = (size_t)kRows * 64 * 4;  // 100 MB
constexpr size_t kGiBytes = (size_t)kRows * 192 * 4; // 300 MB
}

// ------- fc1_k: a[r][64] = relu(x_r . W1^T + b1), split-K 2 waves/row --------
__global__ __launch_bounds__(256, 2)
void fc1_k(const float* __restrict__ obs, const int* __restrict__ agent,
           const float* __restrict__ W1, const float* __restrict__ b1,
           float* __restrict__ a_out) {
  __shared__ float xs[2][2][128];   // [engine][buf][k]
  __shared__ float ps[2][2][64];    // [engine][buf][out] partial sums
  __shared__ float ohs[512];        // ohs[n*64+l] = W1[l][128+agent[n]]
  const int tid = threadIdx.x, lane = tid & 63, w = tid >> 6;
  const int e = w >> 1, p = w & 1;  // engine, k-half

  for (int i = tid; i < 512; i += 256) {
    int n = i >> 6, l = i & 63;
    ohs[i] = W1[(size_t)l * 136 + 128 + agent[n]];
  }

  // lane's weights: W1[lane][p*64 + j], j = 0..63  (16 float4 = 64 VGPRs)
  float4 wv[16];
  #pragma unroll
  for (int k = 0; k < 16; ++k)
    wv[k] = *(const float4*)(W1 + (size_t)lane * 136 + p * 64 + k * 4);
  const float b1r = b1[lane];       // used by finishing wave (p==1)

  constexpr int ROWS = 100;         // 4096 engines x 100 rows = 409600
  const int eng = blockIdx.x * 2 + e;
  const int r0 = eng * ROWS;
  const int et = p * 64 + lane;     // engine-local staging index [0,128)

  // prologue: stage row 0 (own half), load row 1 into register
  xs[e][0][et] = obs[(size_t)r0 * 128 + et];
  float xq = obs[(size_t)(r0 + 1) * 128 + et];
  __syncthreads();                  // covers ohs + row-0 staging

  #pragma unroll 1
  for (int i = 0; i < ROWS; ++i) {
    const int r = r0 + i;
    // store row i+1 (reg) into other buffer; start load of row i+2.
    if (i + 1 < ROWS) xs[e][(i + 1) & 1][et] = xq;
    const int nr = (i + 2 < ROWS) ? (r0 + i + 2) : (r0 + ROWS - 1);
    xq = obs[(size_t)nr * 128 + et];

    const float* xb = xs[e][i & 1] + p * 64;
    float a0 = 0.f, a1 = 0.f, a2 = 0.f, a3 = 0.f;
    #pragma unroll
    for (int k = 0; k < 16; ++k) {
      float4 xp = *(const float4*)(xb + k * 4);   // same-addr broadcast read
      a0 = fmaf(wv[k].x, xp.x, a0);
      a1 = fmaf(wv[k].y, xp.y, a1);
      a2 = fmaf(wv[k].z, xp.z, a2);
      a3 = fmaf(wv[k].w, xp.w, a3);
    }
    const float part = (a0 + a1) + (a2 + a3);
    if (p == 0) ps[e][i & 1][lane] = part;
    __syncthreads();                // ps(i) visible; dbuf protects i+2 reuse
    if (p == 1) {
      float av = part + ps[e][i & 1][lane] + b1r + ohs[(r & 7) * 64 + lane];
      a_out[(size_t)r * 64 + lane] = fmaxf(av, 0.f);
    }
  }
}

// ---------------- gi_k: gi[r][192] = Wih . a_r + bih -------------------------
__global__ __launch_bounds__(256, 2)
void gi_k(const float* __restrict__ a_glob, const float* __restrict__ Wih,
          const float* __restrict__ bih, float* __restrict__ gi_out) {
  __shared__ float as_[4][2][64];
  const int tid = threadIdx.x, lane = tid & 63, w = tid >> 6;

  float wir[64], wiz[64], win_[64];
  #pragma unroll
  for (int k = 0; k < 64; k += 4) {
    *(float4*)&wir[k]  = *(const float4*)(Wih + (size_t)lane * 64 + k);
    *(float4*)&wiz[k]  = *(const float4*)(Wih + (size_t)(64 + lane) * 64 + k);
    *(float4*)&win_[k] = *(const float4*)(Wih + (size_t)(128 + lane) * 64 + k);
  }
  const float bir = bih[lane], biz = bih[64 + lane], bin_ = bih[128 + lane];

  const int gwave = blockIdx.x * 4 + w;   // 2048 waves x 200 rows
  const int r0 = gwave * 200;
  float (*ab)[64] = as_[w];

  ab[0][lane] = a_glob[(size_t)r0 * 64 + lane];
  float qA = a_glob[(size_t)(r0 + 1) * 64 + lane];
  float qB = a_glob[(size_t)(r0 + 2) * 64 + lane];

#define GI_BODY(T, Q, NEXT)                                                    \
  {                                                                            \
    const int t_ = (T);                                                        \
    if (t_ < 199) ab[(t_ + 1) & 1][lane] = Q;                                  \
    const int nr_ = (NEXT) > 199 ? 199 : (NEXT);                               \
    Q = a_glob[(size_t)(r0 + nr_) * 64 + lane];                                \
    const float* ap_ = ab[t_ & 1];                                             \
    float r0a = bir, r1a = 0.f, z0a = biz, z1a = 0.f, n0a = bin_, n1a = 0.f;   \
    _Pragma("unroll") for (int k = 0; k < 64; k += 4) {                        \
      float4 av = *(const float4*)(ap_ + k);                                   \
      r0a = fmaf(wir[k], av.x, r0a);  r1a = fmaf(wir[k + 1], av.y, r1a);       \
      r0a = fmaf(wir[k + 2], av.z, r0a); r1a = fmaf(wir[k + 3], av.w, r1a);    \
      z0a = fmaf(wiz[k], av.x, z0a);  z1a = fmaf(wiz[k + 1], av.y, z1a);       \
      z0a = fmaf(wiz[k + 2], av.z, z0a); z1a = fmaf(wiz[k + 3], av.w, z1a);    \
      n0a = fmaf(win_[k], av.x, n0a); n1a = fmaf(win_[k + 1], av.y, n1a);      \
      n0a = fmaf(win_[k + 2], av.z, n0a); n1a = fmaf(win_[k + 3], av.w, n1a);  \
    }                                                                          \
    float* gp_ = gi_out + (size_t)(r0 + t_) * 192;                             \
    gp_[lane] = r0a + r1a;                                                     \
    gp_[64 + lane] = z0a + z1a;                                                \
    gp_[128 + lane] = n0a + n1a;                                               \
  }

  #pragma unroll 1
  for (int i = 0; i < 200; i += 2) {
    GI_BODY(i + 0, qA, i + 3)
    GI_BODY(i + 1, qB, i + 4)
  }
#undef GI_BODY
}

// -------- gru3_k: 1 wave per sequence, no barriers. bounds(64,1) -------------
__global__ __launch_bounds__(64, 1)
void gru3_k(const float* __restrict__ gi_glob,
            const float* __restrict__ Whh, const float* __restrict__ bhh,
            const float* __restrict__ W2, const float* __restrict__ b2,
            float* __restrict__ out) {
  __shared__ float hs[64];
  const int lane = threadIdx.x;

  float whr[64], whz[64], whn[64];
  #pragma unroll
  for (int k = 0; k < 64; k += 4) {
    *(float4*)&whr[k] = *(const float4*)(Whh + (size_t)lane * 64 + k);
    *(float4*)&whz[k] = *(const float4*)(Whh + (size_t)(64 + lane) * 64 + k);
    *(float4*)&whn[k] = *(const float4*)(Whh + (size_t)(128 + lane) * 64 + k);
  }
  const float bhr = bhh[lane], bhz = bhh[64 + lane], bhn = bhh[128 + lane];
  const int m = lane & 15, qt = lane >> 4;
  float w2r[16];
  #pragma unroll
  for (int j = 0; j < 16; j += 4)
    *(float4*)&w2r[j] = *(const float4*)(W2 + (size_t)m * 64 + qt * 16 + j);
  const float b2r = b2[m];

  const int s = blockIdx.x;              // sequence = b*8 + n
  const int b = s >> 3, n = s & 7;
  const size_t rbase = (size_t)b * 1600 + n;   // r(t) = rbase + 8t

  float* outq  = out;
  float* outmv = out + (size_t)kRows * 16;
  float* outma = outmv + kRows;

  hs[lane] = 0.f;
  float h = 0.f;

  // prefetch gi for t=0 (slot A) and t=1 (slot B)
  const float* gp0 = gi_glob + rbase * 192;
  float gA0 = gp0[lane], gA1 = gp0[64 + lane], gA2 = gp0[128 + lane];
  const float* gp1 = gi_glob + (rbase + 8) * 192;
  float gB0 = gp1[lane], gB1 = gp1[64 + lane], gB2 = gp1[128 + lane];

#define GRU_STEP(T, G0, G1, G2, TN)                                            \
  {                                                                            \
    const int t_ = (T);                                                        \
    const size_t r_ = rbase + (size_t)t_ * 8;                                  \
    float hr0 = bhr, hr1 = 0.f, hz0 = bhz, hz1 = 0.f, hn0 = bhn, hn1 = 0.f;    \
    _Pragma("unroll") for (int k = 0; k < 64; k += 4) {                        \
      float4 hp = *(const float4*)(hs + k);                                    \
      hr0 = fmaf(whr[k], hp.x, hr0);  hr1 = fmaf(whr[k + 1], hp.y, hr1);       \
      hr0 = fmaf(whr[k + 2], hp.z, hr0); hr1 = fmaf(whr[k + 3], hp.w, hr1);    \
      hz0 = fmaf(whz[k], hp.x, hz0);  hz1 = fmaf(whz[k + 1], hp.y, hz1);       \
      hz0 = fmaf(whz[k + 2], hp.z, hz0); hz1 = fmaf(whz[k + 3], hp.w, hz1);    \
      hn0 = fmaf(whn[k], hp.x, hn0);  hn1 = fmaf(whn[k + 1], hp.y, hn1);       \
      hn0 = fmaf(whn[k + 2], hp.z, hn0); hn1 = fmaf(whn[k + 3], hp.w, hn1);    \
    }                                                                          \
    const float rg = 1.f / (1.f + __expf(-((G0) + hr0 + hr1)));                \
    const float zg = 1.f / (1.f + __expf(-((G1) + hz0 + hz1)));                \
    const float e2 = __expf(2.f * ((G2) + rg * (hn0 + hn1)));                  \
    const float ng = 1.f - 2.f / (e2 + 1.f);                                   \
    h = (1.f - zg) * ng + zg * h;                                              \
    hs[lane] = h;                                                              \
    const int tn_ = (TN) > 199 ? 199 : (TN);                                   \
    const float* gp_ = gi_glob + (rbase + (size_t)tn_ * 8) * 192;              \
    G0 = gp_[lane]; G1 = gp_[64 + lane]; G2 = gp_[128 + lane];                 \
    float q0 = 0.f, q1 = 0.f;                                                  \
    _Pragma("unroll") for (int j = 0; j < 16; j += 4) {                        \
      float4 hp = *(const float4*)(hs + qt * 16 + j);                          \
      q0 = fmaf(w2r[j], hp.x, q0);     q1 = fmaf(w2r[j + 1], hp.y, q1);        \
      q0 = fmaf(w2r[j + 2], hp.z, q0); q1 = fmaf(w2r[j + 3], hp.w, q1);        \
    }                                                                          \
    float q = q0 + q1;                                                         \
    q += __shfl_xor(q, 16);                                                    \
    q += __shfl_xor(q, 32);                                                    \
    q += b2r;                                                                  \
    if (lane < 16) outq[r_ * 16 + m] = q;                                      \
    float bv = q; int bi = m;                                                  \
    _Pragma("unroll") for (int d = 1; d < 16; d <<= 1) {                       \
      float ov = __shfl_xor(bv, d, 16);                                        \
      int oi = __shfl_xor(bi, d, 16);                                          \
      if (ov > bv || (ov == bv && oi < bi)) { bv = ov; bi = oi; }              \
    }                                                                          \
    if (lane == 0) { outmv[r_] = bv; outma[r_] = (float)bi; }                  \
  }

  #pragma unroll 1
  for (int t = 0; t < 200; t += 2) {
    GRU_STEP(t, gA0, gA1, gA2, t + 2)
    GRU_STEP(t + 1, gB0, gB1, gB2, t + 3)
  }
#undef GRU_STEP
}

// ---------------- R1 fallback (no/small workspace) ---------------------------
namespace fb {
constexpr int kW1Pitch = 137, kHPitch = 65;
constexpr int OFF_W1 = 0;
constexpr int OFF_WIH = OFF_W1 + 64 * kW1Pitch;
constexpr int OFF_WHH = OFF_WIH + 192 * kHPitch;
constexpr int OFF_W2 = OFF_WHH + 192 * kHPitch;
constexpr int OFF_B1 = OFF_W2 + 16 * kHPitch;
constexpr int OFF_BIH = OFF_B1 + 64;
constexpr int OFF_BHH = OFF_BIH + 192;
constexpr int OFF_B2 = OFF_BHH + 192;
constexpr int LDS_FLOATS = OFF_B2 + 16;
}

__device__ __forceinline__ float bcastf(float v, int l) {
  return __int_as_float(__builtin_amdgcn_readlane(__float_as_int(v), l));
}

__global__ __launch_bounds__(512, 1)
void drqn_fused(const float* __restrict__ obs, const int* __restrict__ agent,
                const float* __restrict__ W1, const float* __restrict__ b1,
                const float* __restrict__ Wih, const float* __restrict__ Whh,
                const float* __restrict__ bih, const float* __restrict__ bhh,
                const float* __restrict__ W2, const float* __restrict__ b2,
                float* __restrict__ out) {
  using namespace fb;
  extern __shared__ float lds[];
  float* W1s = lds + OFF_W1; float* Wihs = lds + OFF_WIH;
  float* Whhs = lds + OFF_WHH; float* W2s = lds + OFF_W2;
  float* b1s = lds + OFF_B1; float* bihs = lds + OFF_BIH;
  float* bhhs = lds + OFF_BHH; float* b2s = lds + OFF_B2;
  const int tid = threadIdx.x;
  for (int i = tid; i < 64 * 136; i += 512) { int r = i / 136, c = i - r * 136; W1s[r * kW1Pitch + c] = W1[i]; }
  for (int i = tid; i < 192 * 64; i += 512) { int r = i >> 6, c = i & 63; Wihs[r * kHPitch + c] = Wih[i]; }
  for (int i = tid; i < 192 * 64; i += 512) { int r = i >> 6, c = i & 63; Whhs[r * kHPitch + c] = Whh[i]; }
  for (int i = tid; i < 16 * 64; i += 512) { int r = i >> 6, c = i & 63; W2s[r * kHPitch + c] = W2[i]; }
  if (tid < 64) b1s[tid] = b1[tid];
  if (tid < 192) bihs[tid] = bih[tid];
  if (tid < 192) bhhs[tid] = bhh[tid];
  if (tid < 16) b2s[tid] = b2[tid];
  __syncthreads();
  const int wave = tid >> 6, lane = tid & 63;
  const int s = blockIdx.x * 8 + wave;
  const int b = s >> 3, n = s & 7;
  const int acol = 128 + agent[n];
  const float* obase = obs + (((size_t)b * kT) * kN + n) * kObs;
  const size_t qbase = (((size_t)b * kT) * kN + n) * kOut;
  const size_t mbase = ((size_t)b * kT) * kN + n;
  float* outq = out;
  float* outmv = out + (size_t)kB * kT * kN * kOut;
  float* outma = outmv + (size_t)kB * kT * kN;
  float h = 0.f;
  float xa = obase[lane], xb = obase[64 + lane];
  #pragma unroll 1
  for (int t = 0; t < kT; ++t) {
    float xan = 0.f, xbn = 0.f;
    if (t + 1 < kT) { const float* p = obase + (size_t)(t + 1) * kN * kObs; xan = p[lane]; xbn = p[64 + lane]; }
    float acc = b1s[lane] + W1s[lane * kW1Pitch + acol];
    #pragma unroll
    for (int k = 0; k < 64; ++k) acc += W1s[lane * kW1Pitch + k] * bcastf(xa, k);
    #pragma unroll
    for (int k = 0; k < 64; ++k) acc += W1s[lane * kW1Pitch + 64 + k] * bcastf(xb, k);
    float a = fmaxf(acc, 0.f);
    float air = bihs[lane], aiz = bihs[64 + lane], ain = bihs[128 + lane];
    #pragma unroll
    for (int k = 0; k < 64; ++k) {
      float sa = bcastf(a, k);
      air += Wihs[lane * kHPitch + k] * sa;
      aiz += Wihs[(64 + lane) * kHPitch + k] * sa;
      ain += Wihs[(128 + lane) * kHPitch + k] * sa;
    }
    float ghr = bhhs[lane], ghz = bhhs[64 + lane], ghn = bhhs[128 + lane];
    #pragma unroll
    for (int k = 0; k < 64; ++k) {
      float sh = bcastf(h, k);
      ghr += Whhs[lane * kHPitch + k] * sh;
      ghz += Whhs[(64 + lane) * kHPitch + k] * sh;
      ghn += Whhs[(128 + lane) * kHPitch + k] * sh;
    }
    float rg = 1.f / (1.f + expf(-(air + ghr)));
    float zg = 1.f / (1.f + expf(-(aiz + ghz)));
    float ng = tanhf(ain + rg * ghn);
    h = (1.f - zg) * ng + zg * h;
    const int m = lane & 15;
    float q = b2s[m];
    #pragma unroll
    for (int k = 0; k < 64; ++k) q += W2s[m * kHPitch + k] * bcastf(h, k);
    if (lane < 16) outq[qbase + (size_t)t * kN * kOut + m] = q;
    float bv = q; int bi = m;
    #pragma unroll
    for (int d = 1; d < 16; d <<= 1) {
      float ov = __shfl_xor(bv, d, 16);
      int oi = __shfl_xor(bi, d, 16);
      if (ov > bv || (ov == bv && oi < bi)) { bv = ov; bi = oi; }
    }
    if (lane == 0) { outmv[mbase + (size_t)t * kN] = bv; outma[mbase + (size_t)t * kN] = (float)bi; }
    xa = xan; xb = xbn;
  }
}

extern "C" void kernel_launch(void* const* d_in, const int* in_sizes, int n_in,
                              void* d_out, int out_size, void* d_ws, size_t ws_size,
                              hipStream_t stream) {
  const float* obs  = (const float*)d_in[0];
  const int* agent  = (const int*)d_in[1];
  const float* W1   = (const float*)d_in[2];
  const float* b1   = (const float*)d_in[3];
  const float* Wih  = (const float*)d_in[4];
  const float* Whh  = (const float*)d_in[5];
  const float* bih  = (const float*)d_in[6];
  const float* bhh  = (const float*)d_in[7];
  const float* W2   = (const float*)d_in[8];
  const float* b2   = (const float*)d_in[9];
  float* out = (float*)d_out;

  if (ws_size >= kABytes + kGiBytes) {
    float* a_buf  = (float*)d_ws;
    float* gi_buf = (float*)((char*)d_ws + kABytes);
    fc1_k<<<dim3(2048), dim3(256), 0, stream>>>(obs, agent, W1, b1, a_buf);
    gi_k<<<dim3(512), dim3(256), 0, stream>>>(a_buf, Wih, bih, gi_buf);
    gru3_k<<<dim3(2048), dim3(64), 0, stream>>>(gi_buf, Whh, bhh, W2, b2, out);
  } else {
    (void)hipFuncSetAttribute((const void*)drqn_fused,
                              hipFuncAttributeMaxDynamicSharedMemorySize,
                              fb::LDS_FLOATS * 4);
    drqn_fused<<<dim3(256), dim3(512), fb::LDS_FLOATS * 4, stream>>>(
        obs, agent, W1, b1, Wih, Whh, bih, bhh, W2, b2, out);
  }
}